// Round 4
// baseline (28.732 us; speedup 1.0000x reference)
//
#include <hip/hip_runtime.h>
#include <stdint.h>

#define BATCH 32
#define NH 12
#define SEQ 785
#define PN 784        // patch_num
#define HDIM 28       // 28*28 == 784
#define VOTE 24       // VOTE_PERHEAD
#define NCHUNK 13     // ceil(784/64)
#define NBIN 128
#define W2 4          // waves per block in count_kernel

// Monotonic float -> uint32: k(a) > k(b) iff a > b (finite floats).
__device__ __forceinline__ uint32_t mono_key(float f) {
    uint32_t u = __float_as_uint(f);
    return (u & 0x80000000u) ? ~u : (u | 0x80000000u);
}

// Wave-parallel radix top-r select over composite keys (value desc, idx asc).
// key[c] valid iff bit c of `alive` set. Calls win(c) exactly r times.
// Keys distinct among alive (index bits). 7-bit digits from SHIFT0 down to 0.
template <int SHIFT0, typename WinF>
__device__ __forceinline__ void wave_select(const uint64_t* key, uint32_t alive,
                                            uint32_t r, uint32_t* histRow,
                                            int lane, WinF&& win) {
    static_assert(SHIFT0 % 7 == 0, "SHIFT0 must be a multiple of 7");
    constexpr int NPASS = SHIFT0 / 7 + 1;
    for (int p = 0; p < NPASS; ++p) {
        const int shift = SHIFT0 - 7 * p;
        histRow[2 * lane]     = 0;
        histRow[2 * lane + 1] = 0;
        __threadfence_block();
        #pragma unroll
        for (int c = 0; c < NCHUNK; ++c)
            if (alive & (1u << c))
                atomicAdd(&histRow[(uint32_t)(key[c] >> shift) & (NBIN - 1)], 1u);
        __threadfence_block();
        uint32_t h0 = histRow[2 * lane];
        uint32_t h1 = histRow[2 * lane + 1];
        uint32_t x = h0 + h1;
        #pragma unroll
        for (int off = 1; off < 64; off <<= 1) {
            uint32_t t = __shfl_down(x, off, 64);
            if (lane + off < 64) x += t;
        }
        uint32_t tail = x - h0 - h1;          // count of digits >= 2*lane+2
        uint32_t Bc = 0, rc = 0, cc = 0;
        int found = 0;
        if (tail < r && r <= tail + h1) {
            Bc = 2 * lane + 1; rc = r - tail; cc = h1; found = 1;
        } else if (tail + h1 < r && r <= tail + h1 + h0) {
            Bc = 2 * lane; rc = r - tail - h1; cc = h0; found = 1;
        }
        uint64_t m = __ballot(found);          // exactly one lane sets found
        int src = (int)(__ffsll((unsigned long long)m) - 1);
        uint32_t B    = __shfl(Bc, src, 64);
        uint32_t rnew = __shfl(rc, src, 64);
        uint32_t cb   = __shfl(cc, src, 64);
        #pragma unroll
        for (int c = 0; c < NCHUNK; ++c) {
            if (alive & (1u << c)) {
                uint32_t bin = (uint32_t)(key[c] >> shift) & (NBIN - 1);
                if (bin > B)      { win(c); alive &= ~(1u << c); }
                else if (bin < B) { alive &= ~(1u << c); }
            }
        }
        r = rnew;
        if (cb == rnew) {
            #pragma unroll
            for (int c = 0; c < NCHUNK; ++c)
                if (alive & (1u << c)) win(c);
            return;
        }
    }
}

// ---- Kernel 1: one wave per (b,h); top-24 vote indices -> sel[bh][24] ----
__launch_bounds__(64)
__global__ void vote_kernel(const float* __restrict__ x, int* __restrict__ sel) {
    const int bh   = blockIdx.x;          // b*NH + h
    const int lane = threadIdx.x;
    __shared__ uint32_t hist[NBIN];
    __shared__ int ticket;
    if (lane == 0) ticket = 0;
    __syncthreads();

    const size_t base = ((size_t)bh * SEQ) * SEQ + 1;   // x[b,h,0,1]
    uint64_t key[NCHUNK];
    #pragma unroll
    for (int c = 0; c < NCHUNK; ++c) {
        int idx = c * 64 + lane;
        float v = (idx < PN) ? x[base + idx] : 0.0f;
        key[c] = ((uint64_t)mono_key(v) << 10) |
                 ((uint32_t)(PN - 1 - idx) & 1023u);
    }
    uint32_t alive = (lane < (PN - 12 * 64)) ? 0x1FFFu : 0x0FFFu;
    int* mysel = sel + bh * VOTE;
    wave_select<35>(key, alive, VOTE, hist, lane,
        [&](int c) { int t = atomicAdd(&ticket, 1); mysel[t] = c * 64 + lane; });
}

// ---- Kernel 2: one wave per batch; count + conv + ranked top-select ----
__launch_bounds__(64 * W2)
__global__ void count_kernel(const int* __restrict__ sel,
                             const float* __restrict__ kern,
                             float* __restrict__ out, int select_num) {
    const int tid  = threadIdx.x;
    const int w    = tid >> 6;
    const int lane = tid & 63;
    const int b    = blockIdx.x * W2 + w;

    __shared__ uint32_t cnt[W2][PN];
    __shared__ uint32_t hist[W2][NBIN];
    __shared__ uint64_t wkey[W2][64];
    __shared__ int      ticket[W2];

    // zero this wave's count grid (wave-private slice, no cross-wave sync needed)
    #pragma unroll
    for (int c = 0; c < NCHUNK; ++c) {
        int i = c * 64 + lane;
        if (i < PN) cnt[w][i] = 0;
    }
    if (lane == 0) ticket[w] = 0;
    __threadfence_block();

    // scatter the 288 votes
    const int* s = sel + b * NH * VOTE;
    for (int i = lane; i < NH * VOTE; i += 64)
        atomicAdd(&cnt[w][s[i]], 1u);
    __threadfence_block();

    float kl[9];
    #pragma unroll
    for (int j = 0; j < 9; ++j) kl[j] = kern[j];

    // 3x3 SAME conv per lane-chunk; write output 1; build select keys
    float* out1 = out + BATCH * select_num + (size_t)b * PN;
    uint64_t key[NCHUNK];
    #pragma unroll
    for (int c = 0; c < NCHUNK; ++c) {
        int i = c * 64 + lane;
        int vi = 0;
        if (i < PN) {
            int y  = i / HDIM;
            int xx = i - y * HDIM;
            float sacc = 0.0f;
            #pragma unroll
            for (int dy = 0; dy < 3; ++dy) {
                int yy = y + dy - 1;
                if (yy < 0 || yy >= HDIM) continue;
                #pragma unroll
                for (int dx = 0; dx < 3; ++dx) {
                    int xc = xx + dx - 1;
                    if (xc < 0 || xc >= HDIM) continue;
                    sacc += kl[dy * 3 + dx] * (float)cnt[w][yy * HDIM + xc];
                }
            }
            out1[i] = sacc;
            vi = (int)sacc;    // conv counts are exact small non-negative ints
        }
        key[c] = ((uint64_t)(uint32_t)vi << 10) |
                 ((uint32_t)(PN - 1 - i) & 1023u);
    }

    uint32_t alive = (lane < (PN - 12 * 64)) ? 0x1FFFu : 0x0FFFu;
    wave_select<14>(key, alive, (uint32_t)select_num, hist[w], lane,
        [&](int c) { int t = atomicAdd(&ticket[w], 1); wkey[w][t] = key[c]; });
    __threadfence_block();

    if (lane < select_num) {
        uint64_t mk = wkey[w][lane];
        int rank = 0;
        for (int m2 = 0; m2 < select_num; ++m2) rank += (wkey[w][m2] > mk) ? 1 : 0;
        int idx = PN - 1 - (int)(mk & 1023u);
        out[(size_t)b * select_num + rank] = (float)(idx + 1);
    }
}

// ---- Fallback: round-3 monolithic kernel (if ws_size too small) ----
__launch_bounds__(768, 1)
__global__ void mhv_mono(const float* __restrict__ x,
                         const float* __restrict__ kern,
                         float* __restrict__ out, int select_num) {
    const int b    = blockIdx.x;
    const int tid  = threadIdx.x;
    const int w    = tid >> 6;
    const int lane = tid & 63;

    __shared__ uint32_t cnt[PN];
    __shared__ float    convf[PN];
    __shared__ uint32_t hist[NH][NBIN];
    __shared__ uint64_t wkey[64];
    __shared__ int      wcnt;
    __shared__ float    kl[9];

    for (int i = tid; i < PN; i += 768) cnt[i] = 0;
    if (tid < 9) kl[tid] = kern[tid];
    if (tid == 0) wcnt = 0;
    __syncthreads();

    {
        const size_t base = ((size_t)(b * NH + w) * SEQ) * SEQ + 1;
        uint64_t key[NCHUNK];
        #pragma unroll
        for (int c = 0; c < NCHUNK; ++c) {
            int idx = c * 64 + lane;
            float v = (idx < PN) ? x[base + idx] : 0.0f;
            key[c] = ((uint64_t)mono_key(v) << 10) |
                     ((uint32_t)(PN - 1 - idx) & 1023u);
        }
        uint32_t alive = (lane < (PN - 12 * 64)) ? 0x1FFFu : 0x0FFFu;
        wave_select<35>(key, alive, VOTE, hist[w], lane,
            [&](int c) { atomicAdd(&cnt[c * 64 + lane], 1u); });
    }
    __syncthreads();

    float* out1 = out + BATCH * select_num;
    for (int i = tid; i < PN; i += 768) {
        int y  = i / HDIM;
        int xx = i - y * HDIM;
        float s = 0.0f;
        #pragma unroll
        for (int dy = 0; dy < 3; ++dy) {
            int yy = y + dy - 1;
            if (yy < 0 || yy >= HDIM) continue;
            #pragma unroll
            for (int dx = 0; dx < 3; ++dx) {
                int xc = xx + dx - 1;
                if (xc < 0 || xc >= HDIM) continue;
                s += kl[dy * 3 + dx] * (float)cnt[yy * HDIM + xc];
            }
        }
        convf[i] = s;
        out1[(size_t)b * PN + i] = s;
    }
    __syncthreads();

    if (w == 0) {
        uint64_t key[NCHUNK];
        #pragma unroll
        for (int c = 0; c < NCHUNK; ++c) {
            int idx = c * 64 + lane;
            int vi = (idx < PN) ? (int)convf[idx] : 0;
            key[c] = ((uint64_t)(uint32_t)vi << 10) |
                     ((uint32_t)(PN - 1 - idx) & 1023u);
        }
        uint32_t alive = (lane < (PN - 12 * 64)) ? 0x1FFFu : 0x0FFFu;
        wave_select<14>(key, alive, (uint32_t)select_num, hist[0], lane,
            [&](int c) { int t = atomicAdd(&wcnt, 1); wkey[t] = key[c]; });
        __threadfence_block();
        if (lane < select_num) {
            uint64_t mk = wkey[lane];
            int rank = 0;
            for (int m2 = 0; m2 < select_num; ++m2) rank += (wkey[m2] > mk) ? 1 : 0;
            int idx = PN - 1 - (int)(mk & 1023u);
            out[(size_t)b * select_num + rank] = (float)(idx + 1);
        }
    }
}

extern "C" void kernel_launch(void* const* d_in, const int* in_sizes, int n_in,
                              void* d_out, int out_size, void* d_ws, size_t ws_size,
                              hipStream_t stream) {
    (void)in_sizes; (void)n_in;
    const float* x    = (const float*)d_in[0];
    const float* kern = (const float*)d_in[1];
    int select_num = (out_size - BATCH * PN) / BATCH;   // = 24
    size_t need = (size_t)BATCH * NH * VOTE * sizeof(int);  // 36,864 B
    if (ws_size >= need) {
        int* sel = (int*)d_ws;
        vote_kernel<<<dim3(BATCH * NH), dim3(64), 0, stream>>>(x, sel);
        count_kernel<<<dim3(BATCH / W2), dim3(64 * W2), 0, stream>>>(
            sel, kern, (float*)d_out, select_num);
    } else {
        mhv_mono<<<dim3(BATCH), dim3(768), 0, stream>>>(x, kern, (float*)d_out, select_num);
    }
}

// Round 5
// 22.311 us; speedup vs baseline: 1.2878x; 1.2878x over previous
//
#include <hip/hip_runtime.h>
#include <stdint.h>

#define BATCH 32
#define NH 12
#define SEQ 785
#define PN 784        // patch_num
#define HDIM 28       // 28*28 == 784
#define VOTE 24       // VOTE_PERHEAD
#define NCHUNK 13     // ceil(784/64)
#define NBIN 128

// Monotonic float -> uint32: k(a) > k(b) iff a > b (finite floats).
__device__ __forceinline__ uint32_t mono_key(float f) {
    uint32_t u = __float_as_uint(f);
    return (u & 0x80000000u) ? ~u : (u | 0x80000000u);
}

// Wave-parallel radix top-r select over 32-bit VALUE keys (desc); ties broken
// by ascending element index (element (c,lane) has index c*64+lane).
// key[c] valid iff bit c of `alive`. Calls win(c) exactly r times.
// 7-bit digits from SHIFT0 down to 0; after the last pass any remaining
// alive elements share one exact key -> ballot rank-select by index.
template <int SHIFT0, typename WinF>
__device__ __forceinline__ void wave_select(const uint32_t* key, uint32_t alive,
                                            uint32_t r, uint32_t* histRow,
                                            int lane, WinF&& win) {
    static_assert(SHIFT0 % 7 == 0, "SHIFT0 must be a multiple of 7");
    constexpr int NPASS = SHIFT0 / 7 + 1;
    #pragma unroll 1
    for (int p = 0; p < NPASS; ++p) {
        const int shift = SHIFT0 - 7 * p;
        histRow[2 * lane]     = 0;
        histRow[2 * lane + 1] = 0;
        __threadfence_block();
        #pragma unroll
        for (int c = 0; c < NCHUNK; ++c)
            if (alive & (1u << c))
                atomicAdd(&histRow[(key[c] >> shift) & (NBIN - 1)], 1u);
        __threadfence_block();
        uint32_t h0 = histRow[2 * lane];
        uint32_t h1 = histRow[2 * lane + 1];
        uint32_t x = h0 + h1;
        #pragma unroll
        for (int off = 1; off < 64; off <<= 1) {
            uint32_t t = __shfl_down(x, off, 64);
            if (lane + off < 64) x += t;
        }
        uint32_t tail = x - h0 - h1;          // count of digits >= 2*lane+2
        uint32_t Bc = 0, rc = 0, cc = 0;
        int found = 0;
        if (tail < r && r <= tail + h1) {
            Bc = 2 * lane + 1; rc = r - tail; cc = h1; found = 1;
        } else if (tail + h1 < r && r <= tail + h1 + h0) {
            Bc = 2 * lane; rc = r - tail - h1; cc = h0; found = 1;
        }
        uint64_t fm = __ballot(found);         // exactly one lane sets found
        int src = (int)(__ffsll((unsigned long long)fm) - 1);
        uint32_t B    = __shfl(Bc, src, 64);
        uint32_t rnew = __shfl(rc, src, 64);
        uint32_t cb   = __shfl(cc, src, 64);
        #pragma unroll
        for (int c = 0; c < NCHUNK; ++c) {
            if (alive & (1u << c)) {
                uint32_t bin = (key[c] >> shift) & (NBIN - 1);
                if (bin > B)      { win(c); alive &= ~(1u << c); }
                else if (bin < B) { alive &= ~(1u << c); }
            }
        }
        r = rnew;
        if (cb == rnew) {                      // threshold bin fully wins
            #pragma unroll
            for (int c = 0; c < NCHUNK; ++c)
                if (alive & (1u << c)) win(c);
            return;
        }
    }
    // Exact-value tie: take the r smallest indices among alive.
    uint32_t rem = r;
    #pragma unroll 1
    for (int c = 0; c < NCHUNK && rem; ++c) {
        int pred = (alive >> c) & 1;
        uint64_t mask = __ballot(pred);
        uint32_t cnt = (uint32_t)__popcll(mask);
        if (pred) {
            uint32_t rank = (uint32_t)__popcll(mask & ((1ull << lane) - 1ull));
            if (rank < rem) win(c);
        }
        rem -= (cnt < rem) ? cnt : rem;
    }
}

// 3x3 SAME conv at cell i of the 28x28 grid stored in cnt.
__device__ __forceinline__ float conv_at(const uint32_t* cnt, const float* kl, int i) {
    int y  = i / HDIM;
    int xx = i - y * HDIM;
    float s = 0.0f;
    #pragma unroll
    for (int dy = 0; dy < 3; ++dy) {
        int yy = y + dy - 1;
        if (yy < 0 || yy >= HDIM) continue;
        #pragma unroll
        for (int dx = 0; dx < 3; ++dx) {
            int xc = xx + dx - 1;
            if (xc < 0 || xc >= HDIM) continue;
            s += kl[dy * 3 + dx] * (float)cnt[yy * HDIM + xc];
        }
    }
    return s;
}

__launch_bounds__(768, 1)
__global__ void mhv_kernel(const float* __restrict__ x,
                           const float* __restrict__ kern,
                           float* __restrict__ out,
                           int select_num) {
    const int b    = blockIdx.x;
    const int tid  = threadIdx.x;
    const int w    = tid >> 6;
    const int lane = tid & 63;

    __shared__ uint32_t cnt[PN];
    __shared__ uint32_t hist[NH][NBIN];
    __shared__ uint32_t wout[64];
    __shared__ int      ticket;

    for (int i = tid; i < PN; i += 768) cnt[i] = 0;
    if (tid == 0) ticket = 0;
    __syncthreads();

    // Prefetch kernel weights (needed post-barrier; latency hides under Phase A).
    float kl[9];
    #pragma unroll
    for (int j = 0; j < 9; ++j) kl[j] = kern[j];

    // ---- Phase A: per-head (wave == head) top-24 vote -----------------------
    {
        const size_t base = ((size_t)(b * NH + w) * SEQ) * SEQ + 1;  // x[b,h,0,1]
        uint32_t key[NCHUNK];
        #pragma unroll
        for (int c = 0; c < NCHUNK; ++c) {
            int idx = c * 64 + lane;
            key[c] = (idx < PN) ? mono_key(x[base + idx]) : 0u;   // pads -> 0 (< T0)
        }
        const uint32_t T0 = mono_key(1.5f);        // survivor threshold
        const uint32_t HI = mono_key(6.0f);        // renorm-shift overflow guard
        uint32_t pred = 0;
        uint32_t total = 0;
        uint64_t anyHi = 0;
        #pragma unroll
        for (int c = 0; c < NCHUNK; ++c) {
            int pv = key[c] >= T0;
            if (pv) pred |= 1u << c;
            total += (uint32_t)__popcll(__ballot(pv));
            anyHi |= __ballot(key[c] >= HI);
        }
        const uint32_t alivefull = (lane < (PN - 12 * 64)) ? 0x1FFFu : 0x0FFFu;
        uint32_t alive = (total >= VOTE) ? pred : alivefull;
        if ((total >= VOTE) && anyHi == 0) {
            // survivors all in [1.5, 6.0): renormalize for digit entropy
            #pragma unroll
            for (int c = 0; c < NCHUNK; ++c) key[c] = (key[c] - T0) << 8;
        }
        wave_select<28>(key, alive, VOTE, hist[w], lane,
            [&](int c) { atomicAdd(&cnt[c * 64 + lane], 1u); });
    }
    __syncthreads();   // all votes in cnt; kern + x loads drained

    // ---- Phase B/C: wave 0 -> full conv + final select; waves 1..11 -> out1 --
    if (w == 0) {
        int vi[NCHUNK];
        uint32_t key[NCHUNK];
        #pragma unroll
        for (int c = 0; c < NCHUNK; ++c) {
            int i = c * 64 + lane;
            vi[c] = (i < PN) ? (int)conv_at(cnt, kl, i) : 0;  // conv is exact int
            key[c] = (uint32_t)vi[c];
        }
        // adaptive threshold: halve from wave-max until >= select_num survive
        int m = vi[0];
        #pragma unroll
        for (int c = 1; c < NCHUNK; ++c) m = (vi[c] > m) ? vi[c] : m;
        #pragma unroll
        for (int off = 1; off < 64; off <<= 1) {
            int t = __shfl_xor(m, off, 64);
            m = (t > m) ? t : m;
        }
        const uint32_t valid = (lane < (PN - 12 * 64)) ? 0x1FFFu : 0x0FFFu;
        uint32_t T = (uint32_t)m;
        uint32_t alive = 0;
        for (;;) {
            uint32_t total = 0;
            uint32_t pr = 0;
            #pragma unroll
            for (int c = 0; c < NCHUNK; ++c) {
                int pv = ((valid >> c) & 1) && (key[c] >= T);
                if (pv) pr |= 1u << c;
                total += (uint32_t)__popcll(__ballot(pv));
            }
            if (total >= (uint32_t)select_num || T == 0) { alive = pr; break; }
            T >>= 1;
        }
        // conv <= 288*16 = 4608 < 2^14 -> 2 radix passes
        wave_select<7>(key, alive, (uint32_t)select_num, hist[0], lane,
            [&](int c) {
                int t = atomicAdd(&ticket, 1);
                wout[t] = ((uint32_t)vi[c] << 10) |
                          (1023u - (uint32_t)(c * 64 + lane));
            });
        __threadfence_block();
        if (lane < select_num) {
            uint32_t pk = wout[lane];
            int rank = 0;
            for (int m2 = 0; m2 < select_num; ++m2) rank += (wout[m2] > pk) ? 1 : 0;
            int idx = 1023 - (int)(pk & 1023u);
            out[(size_t)b * select_num + rank] = (float)(idx + 1);
        }
    } else {
        // waves 1..11 cover the 784 conv-output stores (72 cells each)
        float* out1 = out + BATCH * select_num + (size_t)b * PN;
        int i0 = (w - 1) * 72;
        #pragma unroll
        for (int t = 0; t < 2; ++t) {
            int i = i0 + t * 64 + lane;
            if (i < i0 + 72 && i < PN) out1[i] = conv_at(cnt, kl, i);
        }
    }
}

extern "C" void kernel_launch(void* const* d_in, const int* in_sizes, int n_in,
                              void* d_out, int out_size, void* d_ws, size_t ws_size,
                              hipStream_t stream) {
    (void)in_sizes; (void)n_in; (void)d_ws; (void)ws_size;
    const float* x    = (const float*)d_in[0];
    const float* kern = (const float*)d_in[1];
    int select_num = (out_size - BATCH * PN) / BATCH;   // = 24
    mhv_kernel<<<dim3(BATCH), dim3(768), 0, stream>>>(x, kern, (float*)d_out, select_num);
}

// Round 6
// 18.642 us; speedup vs baseline: 1.5413x; 1.1968x over previous
//
#include <hip/hip_runtime.h>
#include <stdint.h>

#define BATCH 32
#define NH 12
#define SEQ 785
#define PN 784        // patch_num
#define HDIM 28       // 28*28 == 784
#define VOTE 24       // VOTE_PERHEAD
#define NCHUNK 13     // ceil(784/64)
#define NBIN 128

// Monotonic float -> uint32: k(a) > k(b) iff a > b (finite floats).
__device__ __forceinline__ uint32_t mono_key(float f) {
    uint32_t u = __float_as_uint(f);
    return (u & 0x80000000u) ? ~u : (u | 0x80000000u);
}

// Wave-parallel radix top-r select over 32-bit VALUE keys (desc); ties broken
// by ascending element index (element (c,lane) has index c*64+lane).
// key[c] valid iff bit c of `alive`. Calls win(c) exactly r times.
// 7-bit digits from SHIFT0 down to 0; after the last pass any remaining
// alive elements share one exact key -> ballot rank-select by index.
template <int SHIFT0, typename WinF>
__device__ __forceinline__ void wave_select(const uint32_t* key, uint32_t alive,
                                            uint32_t r, uint32_t* histRow,
                                            int lane, WinF&& win) {
    static_assert(SHIFT0 % 7 == 0, "SHIFT0 must be a multiple of 7");
    constexpr int NPASS = SHIFT0 / 7 + 1;
    #pragma unroll 1
    for (int p = 0; p < NPASS; ++p) {
        const int shift = SHIFT0 - 7 * p;
        histRow[2 * lane]     = 0;
        histRow[2 * lane + 1] = 0;
        __threadfence_block();
        #pragma unroll
        for (int c = 0; c < NCHUNK; ++c)
            if (alive & (1u << c))
                atomicAdd(&histRow[(key[c] >> shift) & (NBIN - 1)], 1u);
        __threadfence_block();
        uint32_t h0 = histRow[2 * lane];
        uint32_t h1 = histRow[2 * lane + 1];
        uint32_t x = h0 + h1;
        #pragma unroll
        for (int off = 1; off < 64; off <<= 1) {
            uint32_t t = __shfl_down(x, off, 64);
            if (lane + off < 64) x += t;
        }
        uint32_t tail = x - h0 - h1;          // count of digits >= 2*lane+2
        uint32_t Bc = 0, rc = 0, cc = 0;
        int found = 0;
        if (tail < r && r <= tail + h1) {
            Bc = 2 * lane + 1; rc = r - tail; cc = h1; found = 1;
        } else if (tail + h1 < r && r <= tail + h1 + h0) {
            Bc = 2 * lane; rc = r - tail - h1; cc = h0; found = 1;
        }
        uint64_t fm = __ballot(found);         // exactly one lane sets found
        int src = (int)(__ffsll((unsigned long long)fm) - 1);
        uint32_t B    = __shfl(Bc, src, 64);
        uint32_t rnew = __shfl(rc, src, 64);
        uint32_t cb   = __shfl(cc, src, 64);
        #pragma unroll
        for (int c = 0; c < NCHUNK; ++c) {
            if (alive & (1u << c)) {
                uint32_t bin = (key[c] >> shift) & (NBIN - 1);
                if (bin > B)      { win(c); alive &= ~(1u << c); }
                else if (bin < B) { alive &= ~(1u << c); }
            }
        }
        r = rnew;
        if (cb == rnew) {                      // threshold bin fully wins
            #pragma unroll
            for (int c = 0; c < NCHUNK; ++c)
                if (alive & (1u << c)) win(c);
            return;
        }
    }
    // Exact-value tie: take the r smallest indices among alive.
    uint32_t rem = r;
    #pragma unroll 1
    for (int c = 0; c < NCHUNK && rem; ++c) {
        int pred = (alive >> c) & 1;
        uint64_t mask = __ballot(pred);
        uint32_t cnt = (uint32_t)__popcll(mask);
        if (pred) {
            uint32_t rank = (uint32_t)__popcll(mask & ((1ull << lane) - 1ull));
            if (rank < rem) win(c);
        }
        rem -= (cnt < rem) ? cnt : rem;
    }
}

// 3x3 SAME conv at cell i of the 28x28 grid stored in cnt.
__device__ __forceinline__ float conv_at(const uint32_t* cnt, const float* kl, int i) {
    int y  = i / HDIM;
    int xx = i - y * HDIM;
    float s = 0.0f;
    #pragma unroll
    for (int dy = 0; dy < 3; ++dy) {
        int yy = y + dy - 1;
        if (yy < 0 || yy >= HDIM) continue;
        #pragma unroll
        for (int dx = 0; dx < 3; ++dx) {
            int xc = xx + dx - 1;
            if (xc < 0 || xc >= HDIM) continue;
            s += kl[dy * 3 + dx] * (float)cnt[yy * HDIM + xc];
        }
    }
    return s;
}

__launch_bounds__(768, 1)
__global__ void mhv_kernel(const float* __restrict__ x,
                           const float* __restrict__ kern,
                           float* __restrict__ out,
                           int select_num) {
    const int b    = blockIdx.x;
    const int tid  = threadIdx.x;
    const int w    = tid >> 6;
    const int lane = tid & 63;

    __shared__ uint32_t cnt[PN];
    __shared__ float    convf[PN];
    __shared__ uint32_t hist[NH][NBIN];
    __shared__ uint32_t wout[64];
    __shared__ int      ticket;

    for (int i = tid; i < PN; i += 768) cnt[i] = 0;
    if (tid == 0) ticket = 0;
    __syncthreads();

    // Prefetch kernel weights (latency hides under Phase A).
    float kl[9];
    #pragma unroll
    for (int j = 0; j < 9; ++j) kl[j] = kern[j];

    // ---- Phase A: per-head (wave == head) top-24 vote -----------------------
    {
        const size_t base = ((size_t)(b * NH + w) * SEQ) * SEQ + 1;  // x[b,h,0,1]
        uint32_t key[NCHUNK];
        #pragma unroll
        for (int c = 0; c < NCHUNK; ++c) {
            int idx = c * 64 + lane;
            key[c] = (idx < PN) ? mono_key(x[base + idx]) : 0u;   // pads -> 0 (< T0)
        }
        const uint32_t T0 = mono_key(1.5f);        // survivor threshold
        const uint32_t HI = mono_key(6.0f);        // renorm-shift overflow guard
        uint32_t pred = 0;
        uint32_t total = 0;
        uint64_t anyHi = 0;
        #pragma unroll
        for (int c = 0; c < NCHUNK; ++c) {
            int pv = key[c] >= T0;
            if (pv) pred |= 1u << c;
            total += (uint32_t)__popcll(__ballot(pv));
            anyHi |= __ballot(key[c] >= HI);
        }
        const uint32_t alivefull = (lane < (PN - 12 * 64)) ? 0x1FFFu : 0x0FFFu;
        uint32_t alive = (total >= VOTE) ? pred : alivefull;
        if ((total >= VOTE) && anyHi == 0) {
            // survivors all in [1.5, 6.0): renormalize for digit entropy
            #pragma unroll
            for (int c = 0; c < NCHUNK; ++c) key[c] = (key[c] - T0) << 8;
        }
        wave_select<28>(key, alive, VOTE, hist[w], lane,
            [&](int c) { atomicAdd(&cnt[c * 64 + lane], 1u); });
    }
    __syncthreads();   // all votes in cnt

    // ---- Phase B: distributed conv. Wave w -> chunk w; wave 11 also chunk 12.
    const int i0 = w * 64 + lane;                  // always < 768
    float cv0 = conv_at(cnt, kl, i0);
    convf[i0] = cv0;
    float cv1 = 0.0f;
    if (w == 11 && lane < (PN - 768)) {            // chunk 12 (16 cells)
        cv1 = conv_at(cnt, kl, 768 + lane);
        convf[768 + lane] = cv1;
    }
    __syncthreads();   // convf complete (LDS-only drain; no global stores yet)

    // ---- Phase C: wave 0 selects; all waves store out1 from registers -------
    float* out1 = out + BATCH * select_num + (size_t)b * PN;
    out1[i0] = cv0;                                // issue store, don't wait
    if (w == 11 && lane < (PN - 768)) out1[768 + lane] = cv1;

    if (w == 0) {
        uint32_t key[NCHUNK];
        #pragma unroll
        for (int c = 0; c < NCHUNK; ++c) {
            int i = c * 64 + lane;
            key[c] = (i < PN) ? (uint32_t)(int)convf[i] : 0u;  // exact small ints
        }
        // adaptive threshold: halve from wave-max until >= select_num survive
        uint32_t m = key[0];
        #pragma unroll
        for (int c = 1; c < NCHUNK; ++c) m = (key[c] > m) ? key[c] : m;
        #pragma unroll
        for (int off = 1; off < 64; off <<= 1) {
            uint32_t t = __shfl_xor(m, off, 64);
            m = (t > m) ? t : m;
        }
        const uint32_t valid = (lane < (PN - 12 * 64)) ? 0x1FFFu : 0x0FFFu;
        uint32_t T = m;
        uint32_t alive = 0;
        for (;;) {
            uint32_t total = 0;
            uint32_t pr = 0;
            #pragma unroll
            for (int c = 0; c < NCHUNK; ++c) {
                int pv = ((valid >> c) & 1) && (key[c] >= T);
                if (pv) pr |= 1u << c;
                total += (uint32_t)__popcll(__ballot(pv));
            }
            if (total >= (uint32_t)select_num || T == 0) { alive = pr; break; }
            T >>= 1;
        }
        // conv <= 288*16 = 4608 < 2^14 -> 2 radix passes from shift 7
        wave_select<7>(key, alive, (uint32_t)select_num, hist[0], lane,
            [&](int c) {
                int t = atomicAdd(&ticket, 1);
                wout[t] = (key[c] << 10) |
                          (1023u - (uint32_t)(c * 64 + lane));
            });
        __threadfence_block();
        if (lane < select_num) {
            uint32_t pk = wout[lane];
            int rank = 0;
            for (int m2 = 0; m2 < select_num; ++m2) rank += (wout[m2] > pk) ? 1 : 0;
            int idx = 1023 - (int)(pk & 1023u);
            out[(size_t)b * select_num + rank] = (float)(idx + 1);
        }
    }
}

extern "C" void kernel_launch(void* const* d_in, const int* in_sizes, int n_in,
                              void* d_out, int out_size, void* d_ws, size_t ws_size,
                              hipStream_t stream) {
    (void)in_sizes; (void)n_in; (void)d_ws; (void)ws_size;
    const float* x    = (const float*)d_in[0];
    const float* kern = (const float*)d_in[1];
    int select_num = (out_size - BATCH * PN) / BATCH;   // = 24
    mhv_kernel<<<dim3(BATCH), dim3(768), 0, stream>>>(x, kern, (float*)d_out, select_num);
}